// Round 2
// baseline (219.309 us; speedup 1.0000x reference)
//
#include <hip/hip_runtime.h>
#include <hip/hip_bf16.h>
#include <cstdint>
#include <cstddef>
#include <type_traits>

// B=4, S=2048, D=1024 causal attention head, fp32 in/out.
// R8: gemm_qv ported to 256x256 / BK=64 / 8-wave phased schedule (T2 swizzle +
// T3 phase interleave + T4 counted vmcnt + T5 setprio). sc/pv stay on the
// verified 128^2 2-stage structure (R5-best) pending qv validation.

using bf16 = __hip_bfloat16;
typedef __attribute__((ext_vector_type(8))) short short8;   // 8 bf16 (A/B frag)
typedef __attribute__((ext_vector_type(4))) float f32x4;    // C/D frag

#define NB 4
#define SS 2048
#define DD 1024

// ---------------------------------------------------------------- async 16B global->LDS
__device__ __forceinline__ void async_lds16(const bf16* g, bf16* l) {
  __builtin_amdgcn_global_load_lds(
      (const __attribute__((address_space(1))) void*)g,
      (__attribute__((address_space(3))) void*)l,
      16, 0, 0);  // HW writes lane i's 16B to ldsbase + i*16
}

struct alignas(8) bf16x4s { bf16 a, b, c, d; };

// ---------------------------------------------------------------- fused prep
__global__ __launch_bounds__(256) void prep_kernel(const float* __restrict__ x,
                                                   bf16* __restrict__ xb,
                                                   const float* __restrict__ qk,
                                                   bf16* __restrict__ qkT,
                                                   const float* __restrict__ ov,
                                                   bf16* __restrict__ ovT,
                                                   float* __restrict__ l) {
  __shared__ bf16 tile[64][65];
  const int bx = blockIdx.x;
  if (bx < 8192) {
    int i = (bx * 256 + threadIdx.x) * 4;
    float4 v = *(const float4*)(x + i);
    bf16x4s o{__float2bfloat16(v.x), __float2bfloat16(v.y),
              __float2bfloat16(v.z), __float2bfloat16(v.w)};
    *(bf16x4s*)(xb + i) = o;
  } else if (bx < 8704) {
    const int idx = bx - 8192;
    const float* in = (idx & 256) ? ov : qk;
    bf16* out = (idx & 256) ? ovT : qkT;
    const int rem = idx & 255;
    const int tbx = (rem & 15) * 64;
    const int tby = (rem >> 4) * 64;
    const int tc = threadIdx.x & 63;
    const int tr = threadIdx.x >> 6;
#pragma unroll
    for (int r = tr; r < 64; r += 4)
      tile[tc][r] = __float2bfloat16(in[(size_t)(tby + r) * DD + tbx + tc]);
    __syncthreads();
#pragma unroll
    for (int r = tr; r < 64; r += 4)
      out[(size_t)(tbx + r) * DD + tby + tc] = tile[r][tc];
  } else {
    const int t = (bx - 8704) * 256 + threadIdx.x;
    f32x4 z = {0.f, 0.f, 0.f, 0.f};
    *(f32x4*)(l + t * 4) = z;
  }
}

// ================================================================ 256^2 phased core
// C = A[M,K] * Bt[N,K]^T at (m0,n0). 256x256 tile, BK=64, 8 waves (2Mx4N),
// per-wave output 128x64 (acc[8][4]). 4 phases/K-tile: (rh,kh) in
// {(0,0),(1,0),(0,1),(1,1)}; each = 8 ds_read_b128 + 2 gload_lds + 16 MFMA.
// LDS: [2 buf][256][64] per matrix, 128KB total (dynamic).
// T2 swizzle: 16B-chunk index ^= (row&7); staged via pre-swizzled global src
// (linear gload_lds dest) + swizzled ds_read addr (both-sides, rule 21).
// T4 waits: vmcnt(2) at ph0-end (guards this tile's A1,A3) and ph3-end
// (guards next tile's A0,A2,B0..B3). Never drains mid-loop.
__device__ __forceinline__ void gemm256_core(const bf16* __restrict__ Ab,
                                             const bf16* __restrict__ Bb,
                                             bf16* __restrict__ C,
                                             int N, int K, int m0, int n0, int nk,
                                             bf16* As, bf16* Bs) {
  const int lane = threadIdx.x & 63;
  const int wave = threadIdx.x >> 6;   // 0..7
  const int wr   = wave >> 2;          // 0..1 -> rows wr*128
  const int wc   = wave & 3;           // 0..3 -> cols wc*64
  const int quad = lane >> 4;
  const int r    = lane & 15;

  f32x4 acc[8][4];
#pragma unroll
  for (int i = 0; i < 8; ++i)
#pragma unroll
    for (int n = 0; n < 4; ++n) acc[i][n] = f32x4{0.f, 0.f, 0.f, 0.f};

  // staging: one wave-issue = 8 rows x 64 cols (1KB). lane l -> row l>>3,
  // phys 16B-chunk l&7; logical chunk = (l&7)^(l>>3) (pre-swizzled source).
  const int lrow = lane >> 3;
  const int lsw  = (lane & 7) ^ lrow;
  const long long a_lane = (long long)(m0 + wave * 8 + lrow) * K + lsw * 8;
  const long long b_lane = (long long)(n0 + wave * 8 + lrow) * K + lsw * 8;

  auto stageA = [&](int kt, int rnd, int buf) {
    async_lds16(Ab + a_lane + (long long)(rnd * 64) * K + (long long)kt * 64,
                As + buf * 16384 + (rnd * 64 + wave * 8) * 64);
  };
  auto stageB = [&](int kt, int rnd, int buf) {
    async_lds16(Bb + b_lane + (long long)(rnd * 64) * K + (long long)kt * 64,
                Bs + buf * 16384 + (rnd * 64 + wave * 8) * 64);
  };

  // prologue: K-tile 0 into buf 0, order A0,A2,B0..B3,A1,A3 (first 6 feed ph0/ph2)
  stageA(0, 0, 0); stageA(0, 2, 0);
  stageB(0, 0, 0); stageB(0, 1, 0); stageB(0, 2, 0); stageB(0, 3, 0);
  stageA(0, 1, 0); stageA(0, 3, 0);
  asm volatile("s_waitcnt vmcnt(2)" ::: "memory");
  asm volatile("s_barrier" ::: "memory");

  const int ca0 = (quad ^ (r & 7)) * 8;        // kh=0 swizzled chunk offset (elems)
  const int ca1 = ((4 + quad) ^ (r & 7)) * 8;  // kh=1

  for (int kt = 0; kt < nk; ++kt) {
    const int buf = kt & 1, nxt = buf ^ 1;
    const bool hn = (kt + 1 < nk);
    const bf16* Abuf = As + buf * 16384 + (wr * 128) * 64;
    const bf16* Bbuf = Bs + buf * 16384 + (wc * 64) * 64;

    // wmode: 0 = no wait, 1 = vmcnt(hn?2:0) [ph0], 2 = vmcnt(2) if hn [ph3]
    auto phase = [&](auto RHC, int ca, auto&& stg, int wmode) {
      constexpr int RH = decltype(RHC)::value;
      short8 af[4], bfr[4];
#pragma unroll
      for (int m = 0; m < 4; ++m)
        af[m] = *(const short8*)(Abuf + (RH * 64 + m * 16 + r) * 64 + ca);
#pragma unroll
      for (int n = 0; n < 4; ++n)
        bfr[n] = *(const short8*)(Bbuf + (n * 16 + r) * 64 + ca);
      stg();
      asm volatile("s_barrier" ::: "memory");
      asm volatile("s_waitcnt lgkmcnt(0)" ::: "memory");
      __builtin_amdgcn_sched_barrier(0);
      __builtin_amdgcn_s_setprio(1);
#pragma unroll
      for (int m = 0; m < 4; ++m)
#pragma unroll
        for (int n = 0; n < 4; ++n)
          acc[RH * 4 + m][n] = __builtin_amdgcn_mfma_f32_16x16x32_bf16(
              af[m], bfr[n], acc[RH * 4 + m][n], 0, 0, 0);
      __builtin_amdgcn_s_setprio(0);
      if (wmode == 1) {
        if (hn) asm volatile("s_waitcnt vmcnt(2)" ::: "memory");
        else    asm volatile("s_waitcnt vmcnt(0)" ::: "memory");
      } else if (wmode == 2) {
        if (hn) asm volatile("s_waitcnt vmcnt(2)" ::: "memory");
      }
      asm volatile("s_barrier" ::: "memory");
    };

    phase(std::integral_constant<int, 0>{}, ca0,
          [&] { if (hn) { stageA(kt + 1, 0, nxt); stageA(kt + 1, 2, nxt); } }, 1);
    phase(std::integral_constant<int, 1>{}, ca0,
          [&] { if (hn) { stageB(kt + 1, 0, nxt); stageB(kt + 1, 1, nxt); } }, 0);
    phase(std::integral_constant<int, 0>{}, ca1,
          [&] { if (hn) { stageB(kt + 1, 2, nxt); stageB(kt + 1, 3, nxt); } }, 0);
    phase(std::integral_constant<int, 1>{}, ca1,
          [&] { if (hn) { stageA(kt + 1, 1, nxt); stageA(kt + 1, 3, nxt); } }, 2);
  }

  // epilogue: C/D layout col = lane&15, row = quad*4 + reg (verified m89/m91)
#pragma unroll
  for (int i = 0; i < 8; ++i) {
    const int row0 = m0 + wr * 128 + i * 16 + quad * 4;
#pragma unroll
    for (int n = 0; n < 4; ++n) {
      const int col = n0 + wc * 64 + n * 16 + r;
#pragma unroll
      for (int q = 0; q < 4; ++q)
        C[(long long)(row0 + q) * N + col] = __float2bfloat16(acc[i][n][q]);
    }
  }
}

// ---------------------------------------------------------------- merged Q + V GEMM (256^2)
// Q: z<4, A=xb[z] (M=2048), B=qkT (N=1024): bn=x&3 -> XCD pins one qkT col-panel.
// V: z>=4, A=ovT (M=1024), B=xb[z-4] (N=2048): bm=x&3 -> XCD pins one ovT row-panel.
__global__ __launch_bounds__(512, 2) void gemm_qv256(const bf16* __restrict__ xb,
                                                     const bf16* __restrict__ qkT,
                                                     const bf16* __restrict__ ovT,
                                                     bf16* __restrict__ Qb,
                                                     bf16* __restrict__ Vt) {
  extern __shared__ bf16 lds[];
  bf16* As = lds;            // [2][256][64] = 32K elems
  bf16* Bs = lds + 32768;    // [2][256][64]
  const long long SD = (long long)SS * DD;
  const int z = blockIdx.z;
  if (z < 4) {
    const int bn = blockIdx.x & 3, bm = blockIdx.x >> 2;
    gemm256_core(xb + z * SD, qkT, Qb + z * SD, DD, DD, bm * 256, bn * 256, 16, As, Bs);
  } else {
    const int bm = blockIdx.x & 3, bn = blockIdx.x >> 2;
    gemm256_core(ovT, xb + (z - 4) * SD, Vt + (z - 4) * SD, SS, DD, bm * 256, bn * 256, 16, As, Bs);
  }
}

// ================================================================ 128^2 2-stage core (verified R1-R6)
// EPI: 2 = exp(acc/32) causal -> bf16 + rowsum atomics; 3 = acc/l[row] f32.
template <int EPI, int STAGES>
__device__ __forceinline__ void gemm_core(const bf16* __restrict__ Ab,
                                          const bf16* __restrict__ Bb,
                                          void* __restrict__ C,
                                          int N, int K, int m0, int n0, int nk,
                                          bf16* As, bf16* Bs,
                                          float* __restrict__ l) {
  const int tid  = threadIdx.x;
  const int lane = tid & 63;
  const int wave = tid >> 6;
  const int wm   = (wave >> 1) << 6;
  const int wn   = (wave & 1) << 6;
  const int quad = lane >> 4;
  const int r    = lane & 15;

  f32x4 zero = {0.f, 0.f, 0.f, 0.f};
  f32x4 acc[4][4];
#pragma unroll
  for (int i = 0; i < 4; ++i)
#pragma unroll
    for (int j = 0; j < 4; ++j) acc[i][j] = zero;

  const long long aoff = (long long)(m0 + (tid >> 2)) * K + (tid & 3) * 8;
  const long long boff = (long long)(n0 + (tid >> 2)) * K + (tid & 3) * 8;

  auto stage = [&](int kt, int s) {
    const long long k0 = (long long)kt << 5;
    bf16* lA = As + s * 4096 + wave * 512;
    bf16* lB = Bs + s * 4096 + wave * 512;
    async_lds16(Ab + aoff + k0, lA);
    async_lds16(Ab + aoff + 64LL * K + k0, lA + 2048);
    async_lds16(Bb + boff + k0, lB);
    async_lds16(Bb + boff + 64LL * K + k0, lB + 2048);
  };

  stage(0, 0);
  if (STAGES == 3 && nk > 1) stage(1, 1);

  int s = 0;
  for (int kt = 0; kt < nk; ++kt) {
    if (STAGES == 3) {
      if (kt + 2 < nk) {
        int s2 = s + 2; if (s2 >= 3) s2 -= 3;
        stage(kt + 2, s2);
        asm volatile("s_waitcnt vmcnt(8)" ::: "memory");
      } else if (kt + 1 < nk) {
        asm volatile("s_waitcnt vmcnt(4)" ::: "memory");
      } else {
        asm volatile("s_waitcnt vmcnt(0)" ::: "memory");
      }
    } else {
      if (kt + 1 < nk) {
        stage(kt + 1, s ^ 1);
        asm volatile("s_waitcnt vmcnt(4)" ::: "memory");
      } else {
        asm volatile("s_waitcnt vmcnt(0)" ::: "memory");
      }
    }
    asm volatile("s_barrier" ::: "memory");

    const bf16* Ak = As + s * 4096;
    const bf16* Bk = Bs + s * 4096;
    short8 af[4], bfr[4];
#pragma unroll
    for (int i = 0; i < 4; ++i)
      af[i] = *(const short8*)(Ak + (wm + i * 16 + r) * 32 + quad * 8);
#pragma unroll
    for (int i = 0; i < 4; ++i)
      bfr[i] = *(const short8*)(Bk + (wn + i * 16 + r) * 32 + quad * 8);
#pragma unroll
    for (int i = 0; i < 4; ++i)
#pragma unroll
      for (int j = 0; j < 4; ++j)
        acc[i][j] = __builtin_amdgcn_mfma_f32_16x16x32_bf16(af[i], bfr[j], acc[i][j], 0, 0, 0);

    asm volatile("s_barrier" ::: "memory");
    if (STAGES == 3) { if (++s == 3) s = 0; } else { s ^= 1; }
  }

#pragma unroll
  for (int i = 0; i < 4; ++i) {
    const int row0 = m0 + wm + i * 16 + quad * 4;
    if (EPI == 2) {
      float qs[4] = {0.f, 0.f, 0.f, 0.f};
#pragma unroll
      for (int j = 0; j < 4; ++j) {
        const int col = n0 + wn + j * 16 + r;
#pragma unroll
        for (int q = 0; q < 4; ++q) {
          const int row = row0 + q;
          float v = (col <= row) ? __expf(acc[i][j][q] * 0.03125f) : 0.0f;
          ((bf16*)C)[(long long)row * N + col] = __float2bfloat16(v);
          qs[q] += v;
        }
      }
#pragma unroll
      for (int q = 0; q < 4; ++q) {
#pragma unroll
        for (int off = 1; off < 16; off <<= 1) qs[q] += __shfl_xor(qs[q], off, 64);
        if (r == 0) atomicAdd(&l[row0 + q], qs[q]);
      }
    } else {  // EPI == 3
      float rs[4];
#pragma unroll
      for (int q = 0; q < 4; ++q) rs[q] = 1.0f / l[row0 + q];
#pragma unroll
      for (int j = 0; j < 4; ++j) {
        const int col = n0 + wn + j * 16 + r;
#pragma unroll
        for (int q = 0; q < 4; ++q)
          ((float*)C)[(long long)(row0 + q) * N + col] = acc[i][j][q] * rs[q];
      }
    }
  }
}

// ---------------------------------------------------------------- scores GEMM + fused exp/mask/rowsum
__global__ __launch_bounds__(256) void gemm_sc(const bf16* __restrict__ Qb,
                                               const bf16* __restrict__ xb,
                                               bf16* __restrict__ P,
                                               float* __restrict__ l) {
  __shared__ bf16 As[2 * 4096];
  __shared__ bf16 Bs[2 * 4096];
  const long long SD = (long long)SS * DD;
  const long long SSQ = (long long)SS * SS;
  const int t = blockIdx.x;
  int bm = (int)((sqrtf(8.0f * (float)t + 1.0f) - 1.0f) * 0.5f);
  while ((bm + 1) * (bm + 2) / 2 <= t) ++bm;
  while (bm * (bm + 1) / 2 > t) --bm;
  const int bn = t - bm * (bm + 1) / 2;
  const int b = blockIdx.z;
  gemm_core<2, 2>(Qb + b * SD, xb + b * SD, P + b * SSQ, SS, DD, bm * 128, bn * 128, 32,
                  As, Bs, l + b * SS);
}

// ---------------------------------------------------------------- PV GEMM + fused 1/l
__global__ __launch_bounds__(256) void gemm_pv(const bf16* __restrict__ P,
                                               const bf16* __restrict__ Vt,
                                               const float* __restrict__ l,
                                               float* __restrict__ out) {
  __shared__ bf16 As[2 * 4096];
  __shared__ bf16 Bs[2 * 4096];
  const long long SD = (long long)SS * DD;
  const long long SSQ = (long long)SS * SS;
  const int bm = 15 - blockIdx.y;
  const int m0 = bm * 128;
  const int nk = (m0 + 128) >> 5;
  const int b = blockIdx.z;
  gemm_core<3, 2>(P + b * SSQ, Vt + b * SD, out + b * SD, DD, SS, m0, blockIdx.x * 128, nk,
                  As, Bs, (float*)l + b * SS);
}

// ---------------------------------------------------------------- launch
extern "C" void kernel_launch(void* const* d_in, const int* in_sizes, int n_in,
                              void* d_out, int out_size, void* d_ws, size_t ws_size,
                              hipStream_t stream) {
  const float* x  = (const float*)d_in[0];  // [4,2048,1024]
  const float* qk = (const float*)d_in[1];  // [1024,1024]
  const float* ov = (const float*)d_in[2];  // [1024,1024]
  float* out = (float*)d_out;               // [4,2048,1024] fp32

  char* ws = (char*)d_ws;
  const size_t MB = 1ull << 20;
  bf16*  xb  = (bf16*)(ws + 0);          // 16 MB
  bf16*  qkT = (bf16*)(ws + 16 * MB);    //  2 MB
  bf16*  ovT = (bf16*)(ws + 18 * MB);    //  2 MB
  bf16*  Qb  = (bf16*)(ws + 20 * MB);    // 16 MB
  bf16*  Vt  = (bf16*)(ws + 36 * MB);    // 16 MB  V^T per batch [D, S]
  bf16*  P   = (bf16*)(ws + 52 * MB);    // 32 MB  P' = exp(s/32) bf16
  float* l   = (float*)(ws + 84 * MB);   // 32 KB  row sums [B][S]

  static bool lds_opt_in = false;
  if (!lds_opt_in) {
    hipFuncSetAttribute((const void*)gemm_qv256,
                        hipFuncAttributeMaxDynamicSharedMemorySize, 131072);
    lds_opt_in = true;
  }

  prep_kernel<<<dim3(8712), 256, 0, stream>>>(x, xb, qk, qkT, ov, ovT, l);
  gemm_qv256<<<dim3(32, 1, 8), 512, 131072, stream>>>(xb, qkT, ovT, Qb, Vt);
  gemm_sc<<<dim3(136, 1, 4), 256, 0, stream>>>(Qb, xb, P, l);
  gemm_pv<<<dim3(8, 16, 4), 256, 0, stream>>>(P, Vt, l, out);
}

// Round 3
// 216.932 us; speedup vs baseline: 1.0110x; 1.0110x over previous
//
#include <hip/hip_runtime.h>
#include <hip/hip_bf16.h>
#include <cstdint>
#include <cstddef>
#include <type_traits>

// B=4, S=2048, D=1024 causal attention head, fp32 in/out.
// R9: gemm_pv rework — counters showed pv = 52.6us, MfmaUtil 12.7%, occ 11%,
// ~1850cyc/K-step (latency-bound distance-1 pipeline + 16:1 causal imbalance).
// Fix: 3-stage distance-2 pipeline + explicit bm-pairing (every block = 68
// K-steps, grid 256, 1/CU). qv256 (R8-validated), sc, prep unchanged.

using bf16 = __hip_bfloat16;
typedef __attribute__((ext_vector_type(8))) short short8;   // 8 bf16 (A/B frag)
typedef __attribute__((ext_vector_type(4))) float f32x4;    // C/D frag

#define NB 4
#define SS 2048
#define DD 1024

// ---------------------------------------------------------------- async 16B global->LDS
__device__ __forceinline__ void async_lds16(const bf16* g, bf16* l) {
  __builtin_amdgcn_global_load_lds(
      (const __attribute__((address_space(1))) void*)g,
      (__attribute__((address_space(3))) void*)l,
      16, 0, 0);  // HW writes lane i's 16B to ldsbase + i*16
}

struct alignas(8) bf16x4s { bf16 a, b, c, d; };

// ---------------------------------------------------------------- fused prep
__global__ __launch_bounds__(256) void prep_kernel(const float* __restrict__ x,
                                                   bf16* __restrict__ xb,
                                                   const float* __restrict__ qk,
                                                   bf16* __restrict__ qkT,
                                                   const float* __restrict__ ov,
                                                   bf16* __restrict__ ovT,
                                                   float* __restrict__ l) {
  __shared__ bf16 tile[64][65];
  const int bx = blockIdx.x;
  if (bx < 8192) {
    int i = (bx * 256 + threadIdx.x) * 4;
    float4 v = *(const float4*)(x + i);
    bf16x4s o{__float2bfloat16(v.x), __float2bfloat16(v.y),
              __float2bfloat16(v.z), __float2bfloat16(v.w)};
    *(bf16x4s*)(xb + i) = o;
  } else if (bx < 8704) {
    const int idx = bx - 8192;
    const float* in = (idx & 256) ? ov : qk;
    bf16* out = (idx & 256) ? ovT : qkT;
    const int rem = idx & 255;
    const int tbx = (rem & 15) * 64;
    const int tby = (rem >> 4) * 64;
    const int tc = threadIdx.x & 63;
    const int tr = threadIdx.x >> 6;
#pragma unroll
    for (int r = tr; r < 64; r += 4)
      tile[tc][r] = __float2bfloat16(in[(size_t)(tby + r) * DD + tbx + tc]);
    __syncthreads();
#pragma unroll
    for (int r = tr; r < 64; r += 4)
      out[(size_t)(tbx + r) * DD + tby + tc] = tile[r][tc];
  } else {
    const int t = (bx - 8704) * 256 + threadIdx.x;
    f32x4 z = {0.f, 0.f, 0.f, 0.f};
    *(f32x4*)(l + t * 4) = z;
  }
}

// ================================================================ 256^2 phased core (R8-validated)
__device__ __forceinline__ void gemm256_core(const bf16* __restrict__ Ab,
                                             const bf16* __restrict__ Bb,
                                             bf16* __restrict__ C,
                                             int N, int K, int m0, int n0, int nk,
                                             bf16* As, bf16* Bs) {
  const int lane = threadIdx.x & 63;
  const int wave = threadIdx.x >> 6;   // 0..7
  const int wr   = wave >> 2;          // 0..1 -> rows wr*128
  const int wc   = wave & 3;           // 0..3 -> cols wc*64
  const int quad = lane >> 4;
  const int r    = lane & 15;

  f32x4 acc[8][4];
#pragma unroll
  for (int i = 0; i < 8; ++i)
#pragma unroll
    for (int n = 0; n < 4; ++n) acc[i][n] = f32x4{0.f, 0.f, 0.f, 0.f};

  const int lrow = lane >> 3;
  const int lsw  = (lane & 7) ^ lrow;          // pre-swizzled source chunk
  const long long a_lane = (long long)(m0 + wave * 8 + lrow) * K + lsw * 8;
  const long long b_lane = (long long)(n0 + wave * 8 + lrow) * K + lsw * 8;

  auto stageA = [&](int kt, int rnd, int buf) {
    async_lds16(Ab + a_lane + (long long)(rnd * 64) * K + (long long)kt * 64,
                As + buf * 16384 + (rnd * 64 + wave * 8) * 64);
  };
  auto stageB = [&](int kt, int rnd, int buf) {
    async_lds16(Bb + b_lane + (long long)(rnd * 64) * K + (long long)kt * 64,
                Bs + buf * 16384 + (rnd * 64 + wave * 8) * 64);
  };

  stageA(0, 0, 0); stageA(0, 2, 0);
  stageB(0, 0, 0); stageB(0, 1, 0); stageB(0, 2, 0); stageB(0, 3, 0);
  stageA(0, 1, 0); stageA(0, 3, 0);
  asm volatile("s_waitcnt vmcnt(2)" ::: "memory");
  asm volatile("s_barrier" ::: "memory");

  const int ca0 = (quad ^ (r & 7)) * 8;        // kh=0 swizzled chunk offset
  const int ca1 = ((4 + quad) ^ (r & 7)) * 8;  // kh=1

  for (int kt = 0; kt < nk; ++kt) {
    const int buf = kt & 1, nxt = buf ^ 1;
    const bool hn = (kt + 1 < nk);
    const bf16* Abuf = As + buf * 16384 + (wr * 128) * 64;
    const bf16* Bbuf = Bs + buf * 16384 + (wc * 64) * 64;

    auto phase = [&](auto RHC, int ca, auto&& stg, int wmode) {
      constexpr int RH = decltype(RHC)::value;
      short8 af[4], bfr[4];
#pragma unroll
      for (int m = 0; m < 4; ++m)
        af[m] = *(const short8*)(Abuf + (RH * 64 + m * 16 + r) * 64 + ca);
#pragma unroll
      for (int n = 0; n < 4; ++n)
        bfr[n] = *(const short8*)(Bbuf + (n * 16 + r) * 64 + ca);
      stg();
      asm volatile("s_barrier" ::: "memory");
      asm volatile("s_waitcnt lgkmcnt(0)" ::: "memory");
      __builtin_amdgcn_sched_barrier(0);
      __builtin_amdgcn_s_setprio(1);
#pragma unroll
      for (int m = 0; m < 4; ++m)
#pragma unroll
        for (int n = 0; n < 4; ++n)
          acc[RH * 4 + m][n] = __builtin_amdgcn_mfma_f32_16x16x32_bf16(
              af[m], bfr[n], acc[RH * 4 + m][n], 0, 0, 0);
      __builtin_amdgcn_s_setprio(0);
      if (wmode == 1) {
        if (hn) asm volatile("s_waitcnt vmcnt(2)" ::: "memory");
        else    asm volatile("s_waitcnt vmcnt(0)" ::: "memory");
      } else if (wmode == 2) {
        if (hn) asm volatile("s_waitcnt vmcnt(2)" ::: "memory");
      }
      asm volatile("s_barrier" ::: "memory");
    };

    phase(std::integral_constant<int, 0>{}, ca0,
          [&] { if (hn) { stageA(kt + 1, 0, nxt); stageA(kt + 1, 2, nxt); } }, 1);
    phase(std::integral_constant<int, 1>{}, ca0,
          [&] { if (hn) { stageB(kt + 1, 0, nxt); stageB(kt + 1, 1, nxt); } }, 0);
    phase(std::integral_constant<int, 0>{}, ca1,
          [&] { if (hn) { stageB(kt + 1, 2, nxt); stageB(kt + 1, 3, nxt); } }, 0);
    phase(std::integral_constant<int, 1>{}, ca1,
          [&] { if (hn) { stageA(kt + 1, 1, nxt); stageA(kt + 1, 3, nxt); } }, 2);
  }

#pragma unroll
  for (int i = 0; i < 8; ++i) {
    const int row0 = m0 + wr * 128 + i * 16 + quad * 4;
#pragma unroll
    for (int n = 0; n < 4; ++n) {
      const int col = n0 + wc * 64 + n * 16 + r;
#pragma unroll
      for (int q = 0; q < 4; ++q)
        C[(long long)(row0 + q) * N + col] = __float2bfloat16(acc[i][n][q]);
    }
  }
}

// ---------------------------------------------------------------- merged Q + V GEMM (256^2)
__global__ __launch_bounds__(512, 2) void gemm_qv256(const bf16* __restrict__ xb,
                                                     const bf16* __restrict__ qkT,
                                                     const bf16* __restrict__ ovT,
                                                     bf16* __restrict__ Qb,
                                                     bf16* __restrict__ Vt) {
  extern __shared__ bf16 lds[];
  bf16* As = lds;            // [2][256][64]
  bf16* Bs = lds + 32768;    // [2][256][64]
  const long long SD = (long long)SS * DD;
  const int z = blockIdx.z;
  if (z < 4) {
    const int bn = blockIdx.x & 3, bm = blockIdx.x >> 2;
    gemm256_core(xb + z * SD, qkT, Qb + z * SD, DD, DD, bm * 256, bn * 256, 16, As, Bs);
  } else {
    const int bm = blockIdx.x & 3, bn = blockIdx.x >> 2;
    gemm256_core(ovT, xb + (z - 4) * SD, Vt + (z - 4) * SD, SS, DD, bm * 256, bn * 256, 16, As, Bs);
  }
}

// ================================================================ 128^2 pipelined core
// STAGES=3: distance-2 prefetch (hides ~2x latency). STAGES=2: distance-1.
// EPI: 2 = exp(acc/32) causal -> bf16 + rowsum atomics; 3 = acc/l[row] f32.
template <int EPI, int STAGES>
__device__ __forceinline__ void gemm_core(const bf16* __restrict__ Ab,
                                          const bf16* __restrict__ Bb,
                                          void* __restrict__ C,
                                          int N, int K, int m0, int n0, int nk,
                                          bf16* As, bf16* Bs,
                                          float* __restrict__ l) {
  const int tid  = threadIdx.x;
  const int lane = tid & 63;
  const int wave = tid >> 6;
  const int wm   = (wave >> 1) << 6;
  const int wn   = (wave & 1) << 6;
  const int quad = lane >> 4;
  const int r    = lane & 15;

  f32x4 zero = {0.f, 0.f, 0.f, 0.f};
  f32x4 acc[4][4];
#pragma unroll
  for (int i = 0; i < 4; ++i)
#pragma unroll
    for (int j = 0; j < 4; ++j) acc[i][j] = zero;

  const long long aoff = (long long)(m0 + (tid >> 2)) * K + (tid & 3) * 8;
  const long long boff = (long long)(n0 + (tid >> 2)) * K + (tid & 3) * 8;

  auto stage = [&](int kt, int s) {
    const long long k0 = (long long)kt << 5;
    bf16* lA = As + s * 4096 + wave * 512;
    bf16* lB = Bs + s * 4096 + wave * 512;
    async_lds16(Ab + aoff + k0, lA);
    async_lds16(Ab + aoff + 64LL * K + k0, lA + 2048);
    async_lds16(Bb + boff + k0, lB);
    async_lds16(Bb + boff + 64LL * K + k0, lB + 2048);
  };

  stage(0, 0);
  if (STAGES == 3 && nk > 1) stage(1, 1);

  int s = 0;
  for (int kt = 0; kt < nk; ++kt) {
    if (STAGES == 3) {
      if (kt + 2 < nk) {
        int s2 = s + 2; if (s2 >= 3) s2 -= 3;
        stage(kt + 2, s2);
        asm volatile("s_waitcnt vmcnt(8)" ::: "memory");
      } else if (kt + 1 < nk) {
        asm volatile("s_waitcnt vmcnt(4)" ::: "memory");
      } else {
        asm volatile("s_waitcnt vmcnt(0)" ::: "memory");
      }
    } else {
      if (kt + 1 < nk) {
        stage(kt + 1, s ^ 1);
        asm volatile("s_waitcnt vmcnt(4)" ::: "memory");
      } else {
        asm volatile("s_waitcnt vmcnt(0)" ::: "memory");
      }
    }
    asm volatile("s_barrier" ::: "memory");

    const bf16* Ak = As + s * 4096;
    const bf16* Bk = Bs + s * 4096;
    short8 af[4], bfr[4];
#pragma unroll
    for (int i = 0; i < 4; ++i)
      af[i] = *(const short8*)(Ak + (wm + i * 16 + r) * 32 + quad * 8);
#pragma unroll
    for (int i = 0; i < 4; ++i)
      bfr[i] = *(const short8*)(Bk + (wn + i * 16 + r) * 32 + quad * 8);
#pragma unroll
    for (int i = 0; i < 4; ++i)
#pragma unroll
      for (int j = 0; j < 4; ++j)
        acc[i][j] = __builtin_amdgcn_mfma_f32_16x16x32_bf16(af[i], bfr[j], acc[i][j], 0, 0, 0);

    asm volatile("s_barrier" ::: "memory");
    if (STAGES == 3) { if (++s == 3) s = 0; } else { s ^= 1; }
  }

#pragma unroll
  for (int i = 0; i < 4; ++i) {
    const int row0 = m0 + wm + i * 16 + quad * 4;
    if (EPI == 2) {
      float qs[4] = {0.f, 0.f, 0.f, 0.f};
#pragma unroll
      for (int j = 0; j < 4; ++j) {
        const int col = n0 + wn + j * 16 + r;
#pragma unroll
        for (int q = 0; q < 4; ++q) {
          const int row = row0 + q;
          float v = (col <= row) ? __expf(acc[i][j][q] * 0.03125f) : 0.0f;
          ((bf16*)C)[(long long)row * N + col] = __float2bfloat16(v);
          qs[q] += v;
        }
      }
#pragma unroll
      for (int q = 0; q < 4; ++q) {
#pragma unroll
        for (int off = 1; off < 16; off <<= 1) qs[q] += __shfl_xor(qs[q], off, 64);
        if (r == 0) atomicAdd(&l[row0 + q], qs[q]);
      }
    } else {  // EPI == 3
      float rs[4];
#pragma unroll
      for (int q = 0; q < 4; ++q) rs[q] = 1.0f / l[row0 + q];
#pragma unroll
      for (int j = 0; j < 4; ++j) {
        const int col = n0 + wn + j * 16 + r;
#pragma unroll
        for (int q = 0; q < 4; ++q)
          ((float*)C)[(long long)(row0 + q) * N + col] = acc[i][j][q] * rs[q];
      }
    }
  }
}

// ---------------------------------------------------------------- scores GEMM + fused exp/mask/rowsum
__global__ __launch_bounds__(256) void gemm_sc(const bf16* __restrict__ Qb,
                                               const bf16* __restrict__ xb,
                                               bf16* __restrict__ P,
                                               float* __restrict__ l) {
  __shared__ bf16 As[2 * 4096];
  __shared__ bf16 Bs[2 * 4096];
  const long long SD = (long long)SS * DD;
  const long long SSQ = (long long)SS * SS;
  const int t = blockIdx.x;
  int bm = (int)((sqrtf(8.0f * (float)t + 1.0f) - 1.0f) * 0.5f);
  while ((bm + 1) * (bm + 2) / 2 <= t) ++bm;
  while (bm * (bm + 1) / 2 > t) --bm;
  const int bn = t - bm * (bm + 1) / 2;
  const int b = blockIdx.z;
  gemm_core<2, 2>(Qb + b * SD, xb + b * SD, P + b * SSQ, SS, DD, bm * 128, bn * 128, 32,
                  As, Bs, l + b * SS);
}

// ---------------------------------------------------------------- PV GEMM + fused 1/l
// R9: 3-stage distance-2 + bm-pairing. Block (bx, p, b) does bm=15-p then
// bm=p: exactly 68 K-steps per block, grid 256 (1/CU, zero tail).
// x fastest -> XCD ~ bx: one 512KB Vt panel x4 batches = 2MB pinned per L2.
// vmcnt(0) between tiles: epilogue stores share the vmcnt counter with the
// next tile's staging loads; a counted wait would not guarantee LDS landed.
__global__ __launch_bounds__(256) void gemm_pv(const bf16* __restrict__ P,
                                               const bf16* __restrict__ Vt,
                                               const float* __restrict__ l,
                                               float* __restrict__ out) {
  __shared__ bf16 As[3 * 4096];
  __shared__ bf16 Bs[3 * 4096];
  const long long SD = (long long)SS * DD;
  const long long SSQ = (long long)SS * SS;
  const int b = blockIdx.z;
  const int n0 = blockIdx.x * 128;
  const int bmL = 15 - (int)blockIdx.y;   // long tile: nk = 4*(16-p)
  const int bmS = (int)blockIdx.y;        // short tile: nk = 4*(p+1)

  gemm_core<3, 3>(P + b * SSQ, Vt + b * SD, out + b * SD, DD, SS,
                  bmL * 128, n0, (bmL * 128 + 128) >> 5, As, Bs, (float*)l + b * SS);
  asm volatile("s_waitcnt vmcnt(0)" ::: "memory");
  __syncthreads();
  gemm_core<3, 3>(P + b * SSQ, Vt + b * SD, out + b * SD, DD, SS,
                  bmS * 128, n0, (bmS * 128 + 128) >> 5, As, Bs, (float*)l + b * SS);
}

// ---------------------------------------------------------------- launch
extern "C" void kernel_launch(void* const* d_in, const int* in_sizes, int n_in,
                              void* d_out, int out_size, void* d_ws, size_t ws_size,
                              hipStream_t stream) {
  const float* x  = (const float*)d_in[0];  // [4,2048,1024]
  const float* qk = (const float*)d_in[1];  // [1024,1024]
  const float* ov = (const float*)d_in[2];  // [1024,1024]
  float* out = (float*)d_out;               // [4,2048,1024] fp32

  char* ws = (char*)d_ws;
  const size_t MB = 1ull << 20;
  bf16*  xb  = (bf16*)(ws + 0);          // 16 MB
  bf16*  qkT = (bf16*)(ws + 16 * MB);    //  2 MB
  bf16*  ovT = (bf16*)(ws + 18 * MB);    //  2 MB
  bf16*  Qb  = (bf16*)(ws + 20 * MB);    // 16 MB
  bf16*  Vt  = (bf16*)(ws + 36 * MB);    // 16 MB  V^T per batch [D, S]
  bf16*  P   = (bf16*)(ws + 52 * MB);    // 32 MB  P' = exp(s/32) bf16
  float* l   = (float*)(ws + 84 * MB);   // 32 KB  row sums [B][S]

  static bool lds_opt_in = false;
  if (!lds_opt_in) {
    hipFuncSetAttribute((const void*)gemm_qv256,
                        hipFuncAttributeMaxDynamicSharedMemorySize, 131072);
    lds_opt_in = true;
  }

  prep_kernel<<<dim3(8712), 256, 0, stream>>>(x, xb, qk, qkT, ov, ovT, l);
  gemm_qv256<<<dim3(32, 1, 8), 512, 131072, stream>>>(xb, qkT, ovT, Qb, Vt);
  gemm_sc<<<dim3(136, 1, 4), 256, 0, stream>>>(Qb, xb, P, l);
  gemm_pv<<<dim3(8, 8, 4), 256, 0, stream>>>(P, Vt, l, out);
}